// Round 8
// baseline (2050.421 us; speedup 1.0000x reference)
//
#include <hip/hip_runtime.h>
#include <hip/hip_bf16.h>
#include <stdint.h>

typedef __bf16 bf16x8 __attribute__((ext_vector_type(8)));
typedef float  f32x4  __attribute__((ext_vector_type(4)));

#define BAR()  asm volatile("s_waitcnt lgkmcnt(0)\n\ts_barrier" ::: "memory")
#define SB()   __builtin_amdgcn_sched_barrier(0)

static __device__ __forceinline__ float sigm(float x) {
  return __builtin_amdgcn_rcpf(1.0f + __builtin_amdgcn_exp2f(x * -1.4426950408889634f));
}
static __device__ __forceinline__ float tanh_fast(float x) {
  return 1.0f - 2.0f * __builtin_amdgcn_rcpf(1.0f + __builtin_amdgcn_exp2f(x * 2.8853900817779268f));
}
static __device__ __forceinline__ unsigned short f2bf(float f) {
  return __builtin_bit_cast(unsigned short, (__bf16)f);
}
static __device__ __forceinline__ float bf2f(unsigned short u) {
  union { uint32_t i; float f; } v; v.i = ((uint32_t)u) << 16; return v.f;
}
static __device__ __forceinline__ void async16(const float* g, float* l) {
  __builtin_amdgcn_global_load_lds((__attribute__((address_space(1))) void*)g,
                                   (__attribute__((address_space(3))) void*)l, 16, 0, 0);
}

// 64 WGs x 512 threads persistent; wave wid owns h-cols wid*16..+15 (gate types
// i,f,g,o as its 4 N-tiles). One barrier/step: region t = A(t) + B(t-1).
// Latency plan: issue x+h0 reads at region top; h1+wf(kk0) reads hide under the
// pure-register wih1 MFMA block (h0 frags reused for Whh0 AND Wih1); whh1 loop
// prefetches wf(kk+1) and interleaves one r-slice of pw0 per cluster.
#define PW0(r) { float iv=sigm(acc0[0][r]); float fv=sigm(acc0[1][r]); \
  float gv=tanh_fast(acc0[2][r]); float ov=sigm(acc0[3][r]); \
  float c=fv*c0r[r]+iv*gv; c0r[r]=c; \
  *(unsigned short*)(hw0+(r)*16)=f2bf(ov*tanh_fast(c)); }

__global__ __launch_bounds__(512) __attribute__((amdgpu_waves_per_eu(2, 2)))
void fraud_lstm_kernel(
    const float* __restrict__ x,     const float* __restrict__ Wproj,
    const float* __restrict__ bproj, const float* __restrict__ Wih0,
    const float* __restrict__ Whh0,  const float* __restrict__ bih0,
    const float* __restrict__ bhh0,  const float* __restrict__ Wih1,
    const float* __restrict__ Whh1,  const float* __restrict__ bih1,
    const float* __restrict__ bhh1,  const float* __restrict__ Wh1,
    const float* __restrict__ bh1,   const float* __restrict__ Wh2,
    const float* __restrict__ bh2,   float* __restrict__ out)
{
  // LDS: 131072 + 8192 + 8192 + 12288 = 159744 B
  __shared__ unsigned short sWf[65536];     // Whh1 frags [wid][n*4+kk][lane][8]; also Wproj stage
  __shared__ unsigned short sH0f[2][2048];  // h0 dbuf, frag-linear [kk][lane][8]
  __shared__ unsigned short sH1f[2][2048];  // h1 dbuf
  __shared__ float sXB[3*1024];             // x triple buffer, frag-linear [kk][half][lane][4]

  const int tid  = threadIdx.x;
  const int lane = tid & 63;
  const int wid  = tid >> 6;
  const int lr   = lane & 15;
  const int lg   = lane >> 4;
  const int b0   = blockIdx.x * 16;
  const int g0   = wid*16 + lr;

  // ---------------- stage Wproj (f32 [64][64]) into sWf ----------------
  {
    float* sWp = reinterpret_cast<float*>(sWf);
    for (int i = tid; i < 4096; i += 512) sWp[i] = Wproj[i];
  }
  BAR();

  // ---------------- fold W0 = Wih0 @ Wproj (per-lane f32); fold biases ----------------
  float w0a[2][4][8];
  #pragma unroll
  for (int kk = 0; kk < 2; ++kk)
    #pragma unroll
    for (int n = 0; n < 4; ++n)
      #pragma unroll
      for (int j = 0; j < 8; ++j) w0a[kk][n][j] = 0.f;
  float bacc[4] = {0.f, 0.f, 0.f, 0.f};
  {
    const float* sWp = reinterpret_cast<const float*>(sWf);
    #pragma unroll 2
    for (int p = 0; p < 64; ++p) {
      float av[4];
      #pragma unroll
      for (int n = 0; n < 4; ++n) av[n] = Wih0[(n*128 + g0)*64 + p];
      float bp = bproj[p];
      #pragma unroll
      for (int n = 0; n < 4; ++n) bacc[n] += av[n] * bp;
      #pragma unroll
      for (int kk = 0; kk < 2; ++kk) {
        f32x4 wa = *(const f32x4*)&sWp[p*64 + kk*32 + lg*8];
        f32x4 wb = *(const f32x4*)&sWp[p*64 + kk*32 + lg*8 + 4];
        #pragma unroll
        for (int n = 0; n < 4; ++n)
          #pragma unroll
          for (int j = 0; j < 4; ++j) {
            w0a[kk][n][j]     += av[n] * wa[j];
            w0a[kk][n][4 + j] += av[n] * wb[j];
          }
      }
    }
  }
  bf16x8 w0f[2][4];
  #pragma unroll
  for (int kk = 0; kk < 2; ++kk)
    #pragma unroll
    for (int n = 0; n < 4; ++n)
      #pragma unroll
      for (int j = 0; j < 8; ++j) w0f[kk][n][j] = (__bf16)w0a[kk][n][j];

  float b0r[4], b1r[4];
  #pragma unroll
  for (int n = 0; n < 4; ++n) {
    const int g = n*128 + g0;
    b0r[n] = bih0[g] + bhh0[g] + bacc[n];
    b1r[n] = bih1[g] + bhh1[g];
  }
  BAR();   // Wproj stage dead; sWf free

  // ---------------- whh0, wih1 -> regs; Whh1 -> LDS frag-linear ----------------
  bf16x8 whh0[4][4], wih1[4][4];
  #pragma unroll
  for (int n = 0; n < 4; ++n)
    #pragma unroll
    for (int kk = 0; kk < 4; ++kk) {
      const int ro = (n*128 + g0)*128 + kk*32 + lg*8;
      const float* p0 = Whh0 + ro;
      const float* p1 = Wih1 + ro;
      #pragma unroll
      for (int j = 0; j < 8; ++j) {
        whh0[n][kk][j] = (__bf16)p0[j];
        wih1[n][kk][j] = (__bf16)p1[j];
      }
    }
  #pragma unroll
  for (int n = 0; n < 4; ++n)
    #pragma unroll
    for (int kk = 0; kk < 4; ++kk) {
      const int ro = (n*128 + g0)*128 + kk*32 + lg*8;
      const float* p2 = Whh1 + ro;
      bf16x8 w;
      #pragma unroll
      for (int j = 0; j < 8; ++j) w[j] = (__bf16)p2[j];
      *(bf16x8*)&sWf[((wid*16 + n*4 + kk)*64 + lane)*8] = w;
    }

  for (int i = tid; i < 2048; i += 512) {
    sH0f[0][i] = 0; sH0f[1][i] = 0; sH1f[0][i] = 0; sH1f[1][i] = 0;
  }

  // ---------------- x staging: frag-linear, per-lane permuted global source ----------------
  const float* xw = x + (size_t)(b0 + (lane & 15)) * (512*64)
                      + ((wid >> 1) & 1) * 32 + (lane >> 4) * 8 + (wid & 1) * 4;
  if (wid < 4) {
    async16(xw,      &sXB[0*1024 + wid*256]);   // x(0) -> buf0
    async16(xw + 64, &sXB[1*1024 + wid*256]);   // x(1) -> buf1
    asm volatile("s_waitcnt vmcnt(1)" ::: "memory");
  }
  BAR();

  const int hwb = (g0 >> 5)*1024 + ((g0 >> 3) & 3)*256 + (g0 & 7)*2 + lg*64;
  const int lb  = lane * 16;

  f32x4 c0r = {0.f,0.f,0.f,0.f}, c1r = {0.f,0.f,0.f,0.f};
  int bufR = 0, bufW = 2;

  // ================ main loop: region t = A(t) + B(t-1), one barrier ================
  #pragma unroll 1
  for (int t = 0; t < 512; ++t) {
    const int cur = t & 1;

    if (wid < 4 && t < 510) async16(xw + (t + 2)*64, &sXB[bufW*1024 + wid*256]);

    const char* xp  = (const char*)sXB + bufR*4096 + lb;
    const char* h0p = (const char*)sH0f[cur ^ 1] + lb;
    const char* h1p = (const char*)sH1f[cur] + lb;
    const char* wp  = (const char*)sWf + wid*16384 + lb;
    char* hw0 = (char*)sH0f[cur] + hwb;

    // ---- up-front loads: x (4) + h0 (4) ----
    f32x4 xv0 = *(const f32x4*)(xp);
    f32x4 xv1 = *(const f32x4*)(xp + 1024);
    f32x4 xv2 = *(const f32x4*)(xp + 2048);
    f32x4 xv3 = *(const f32x4*)(xp + 3072);
    bf16x8 h0a0 = *(const bf16x8*)(h0p);
    bf16x8 h0a1 = *(const bf16x8*)(h0p + 1024);
    bf16x8 h0a2 = *(const bf16x8*)(h0p + 2048);
    bf16x8 h0a3 = *(const bf16x8*)(h0p + 3072);

    // ---- A(t): x part ----
    f32x4 acc0[4];
    #pragma unroll
    for (int n = 0; n < 4; ++n) acc0[n] = f32x4{b0r[n], b0r[n], b0r[n], b0r[n]};
    {
      bf16x8 xa, xb;
      #pragma unroll
      for (int j = 0; j < 4; ++j) {
        xa[j] = (__bf16)xv0[j]; xa[4+j] = (__bf16)xv1[j];
        xb[j] = (__bf16)xv2[j]; xb[4+j] = (__bf16)xv3[j];
      }
      #pragma unroll
      for (int n = 0; n < 4; ++n)
        acc0[n] = __builtin_amdgcn_mfma_f32_16x16x32_bf16(xa, w0f[0][n], acc0[n], 0, 0, 0);
      #pragma unroll
      for (int n = 0; n < 4; ++n)
        acc0[n] = __builtin_amdgcn_mfma_f32_16x16x32_bf16(xb, w0f[1][n], acc0[n], 0, 0, 0);
    }
    // ---- A(t): h0(t-1) @ Whh0^T ----
    #pragma unroll
    for (int n = 0; n < 4; ++n)
      acc0[n] = __builtin_amdgcn_mfma_f32_16x16x32_bf16(h0a0, whh0[n][0], acc0[n], 0, 0, 0);
    #pragma unroll
    for (int n = 0; n < 4; ++n)
      acc0[n] = __builtin_amdgcn_mfma_f32_16x16x32_bf16(h0a1, whh0[n][1], acc0[n], 0, 0, 0);
    #pragma unroll
    for (int n = 0; n < 4; ++n)
      acc0[n] = __builtin_amdgcn_mfma_f32_16x16x32_bf16(h0a2, whh0[n][2], acc0[n], 0, 0, 0);
    #pragma unroll
    for (int n = 0; n < 4; ++n)
      acc0[n] = __builtin_amdgcn_mfma_f32_16x16x32_bf16(h0a3, whh0[n][3], acc0[n], 0, 0, 0);
    SB();

    // ---- issue h1 (4) + wf kk0 (4); they hide under the wih1 block ----
    bf16x8 h1a0 = *(const bf16x8*)(h1p);
    bf16x8 h1a1 = *(const bf16x8*)(h1p + 1024);
    bf16x8 h1a2 = *(const bf16x8*)(h1p + 2048);
    bf16x8 h1a3 = *(const bf16x8*)(h1p + 3072);
    bf16x8 wfa0 = *(const bf16x8*)(wp);
    bf16x8 wfa1 = *(const bf16x8*)(wp + 4096);
    bf16x8 wfa2 = *(const bf16x8*)(wp + 8192);
    bf16x8 wfa3 = *(const bf16x8*)(wp + 12288);

    // ---- B(t-1): h0(t-1) @ Wih1^T (pure-register block, reuses h0a) ----
    f32x4 acc1[4];
    #pragma unroll
    for (int n = 0; n < 4; ++n) acc1[n] = f32x4{b1r[n], b1r[n], b1r[n], b1r[n]};
    #pragma unroll
    for (int n = 0; n < 4; ++n)
      acc1[n] = __builtin_amdgcn_mfma_f32_16x16x32_bf16(h0a0, wih1[n][0], acc1[n], 0, 0, 0);
    #pragma unroll
    for (int n = 0; n < 4; ++n)
      acc1[n] = __builtin_amdgcn_mfma_f32_16x16x32_bf16(h0a1, wih1[n][1], acc1[n], 0, 0, 0);
    #pragma unroll
    for (int n = 0; n < 4; ++n)
      acc1[n] = __builtin_amdgcn_mfma_f32_16x16x32_bf16(h0a2, wih1[n][2], acc1[n], 0, 0, 0);
    #pragma unroll
    for (int n = 0; n < 4; ++n)
      acc1[n] = __builtin_amdgcn_mfma_f32_16x16x32_bf16(h0a3, wih1[n][3], acc1[n], 0, 0, 0);
    SB();

    // ---- B(t-1): h1(t-2) @ Whh1^T, wf depth-1 prefetch, pw0 interleaved ----
    {
      // kk = 0 (prefetch kk=1)
      bf16x8 wfb0 = *(const bf16x8*)(wp + 1024);
      bf16x8 wfb1 = *(const bf16x8*)(wp + 4096 + 1024);
      bf16x8 wfb2 = *(const bf16x8*)(wp + 8192 + 1024);
      bf16x8 wfb3 = *(const bf16x8*)(wp + 12288 + 1024);
      acc1[0] = __builtin_amdgcn_mfma_f32_16x16x32_bf16(h1a0, wfa0, acc1[0], 0, 0, 0);
      acc1[1] = __builtin_amdgcn_mfma_f32_16x16x32_bf16(h1a0, wfa1, acc1[1], 0, 0, 0);
      acc1[2] = __builtin_amdgcn_mfma_f32_16x16x32_bf16(h1a0, wfa2, acc1[2], 0, 0, 0);
      acc1[3] = __builtin_amdgcn_mfma_f32_16x16x32_bf16(h1a0, wfa3, acc1[3], 0, 0, 0);
      PW0(0);
      SB();
      // kk = 1 (prefetch kk=2)
      wfa0 = *(const bf16x8*)(wp + 2048);
      wfa1 = *(const bf16x8*)(wp + 4096 + 2048);
      wfa2 = *(const bf16x8*)(wp + 8192 + 2048);
      wfa3 = *(const bf16x8*)(wp + 12288 + 2048);
      acc1[0] = __builtin_amdgcn_mfma_f32_16x16x32_bf16(h1a1, wfb0, acc1[0], 0, 0, 0);
      acc1[1] = __builtin_amdgcn_mfma_f32_16x16x32_bf16(h1a1, wfb1, acc1[1], 0, 0, 0);
      acc1[2] = __builtin_amdgcn_mfma_f32_16x16x32_bf16(h1a1, wfb2, acc1[2], 0, 0, 0);
      acc1[3] = __builtin_amdgcn_mfma_f32_16x16x32_bf16(h1a1, wfb3, acc1[3], 0, 0, 0);
      PW0(1);
      SB();
      // kk = 2 (prefetch kk=3)
      wfb0 = *(const bf16x8*)(wp + 3072);
      wfb1 = *(const bf16x8*)(wp + 4096 + 3072);
      wfb2 = *(const bf16x8*)(wp + 8192 + 3072);
      wfb3 = *(const bf16x8*)(wp + 12288 + 3072);
      acc1[0] = __builtin_amdgcn_mfma_f32_16x16x32_bf16(h1a2, wfa0, acc1[0], 0, 0, 0);
      acc1[1] = __builtin_amdgcn_mfma_f32_16x16x32_bf16(h1a2, wfa1, acc1[1], 0, 0, 0);
      acc1[2] = __builtin_amdgcn_mfma_f32_16x16x32_bf16(h1a2, wfa2, acc1[2], 0, 0, 0);
      acc1[3] = __builtin_amdgcn_mfma_f32_16x16x32_bf16(h1a2, wfa3, acc1[3], 0, 0, 0);
      PW0(2);
      SB();
      // kk = 3
      acc1[0] = __builtin_amdgcn_mfma_f32_16x16x32_bf16(h1a3, wfb0, acc1[0], 0, 0, 0);
      acc1[1] = __builtin_amdgcn_mfma_f32_16x16x32_bf16(h1a3, wfb1, acc1[1], 0, 0, 0);
      acc1[2] = __builtin_amdgcn_mfma_f32_16x16x32_bf16(h1a3, wfb2, acc1[2], 0, 0, 0);
      acc1[3] = __builtin_amdgcn_mfma_f32_16x16x32_bf16(h1a3, wfb3, acc1[3], 0, 0, 0);
      PW0(3);
      SB();
    }

    // ---- pointwise 1 -> h1(t-1); skipped at t=0 (h1(-1) must stay 0) ----
    if (t > 0) {
      char* hw = (char*)sH1f[cur ^ 1] + hwb;
      #pragma unroll
      for (int r = 0; r < 4; ++r) {
        float iv = sigm(acc1[0][r]);
        float fv = sigm(acc1[1][r]);
        float gv = tanh_fast(acc1[2][r]);
        float ov = sigm(acc1[3][r]);
        float c  = fv * c1r[r] + iv * gv;
        c1r[r] = c;
        *(unsigned short*)(hw + r*16) = f2bf(ov * tanh_fast(c));
      }
    }

    if (wid < 4) {
      if (t < 510) asm volatile("s_waitcnt vmcnt(1)" ::: "memory");
      else         asm volatile("s_waitcnt vmcnt(0)" ::: "memory");
    }
    BAR();   // h0(t), h1(t-1), x(t+1) visible

    bufR = (bufR == 2) ? 0 : bufR + 1;
    bufW = (bufW == 2) ? 0 : bufW + 1;
  }

  // ================ epilogue: B(511) ================
  {
    f32x4 acc1[4];
    #pragma unroll
    for (int n = 0; n < 4; ++n) acc1[n] = f32x4{b1r[n], b1r[n], b1r[n], b1r[n]};
    const char* h0p = (const char*)sH0f[1] + lb;   // h0(511)
    #pragma unroll
    for (int kk = 0; kk < 4; ++kk) {
      bf16x8 ha = *(const bf16x8*)(h0p + kk*1024);
      #pragma unroll
      for (int n = 0; n < 4; ++n)
        acc1[n] = __builtin_amdgcn_mfma_f32_16x16x32_bf16(ha, wih1[n][kk], acc1[n], 0, 0, 0);
    }
    const char* h1p = (const char*)sH1f[0] + lb;   // h1(510)
    const char* wp  = (const char*)sWf + wid*16384 + lb;
    #pragma unroll
    for (int kk = 0; kk < 4; ++kk) {
      bf16x8 ha = *(const bf16x8*)(h1p + kk*1024);
      #pragma unroll
      for (int n = 0; n < 4; ++n) {
        bf16x8 wf = *(const bf16x8*)(wp + (n*4 + kk)*1024);
        acc1[n] = __builtin_amdgcn_mfma_f32_16x16x32_bf16(ha, wf, acc1[n], 0, 0, 0);
      }
    }
    char* hw = (char*)sH1f[1] + hwb;               // h1(511)
    #pragma unroll
    for (int r = 0; r < 4; ++r) {
      float iv = sigm(acc1[0][r]);
      float fv = sigm(acc1[1][r]);
      float gv = tanh_fast(acc1[2][r]);
      float ov = sigm(acc1[3][r]);
      float c  = fv * c1r[r] + iv * gv;
      c1r[r] = c;
      *(unsigned short*)(hw + r*16) = f2bf(ov * tanh_fast(c));
    }
    BAR();
  }

  // ---------------- head: hid = relu(h1@Wh1^T + bh1); out = hid@Wh2^T + bh2 ----------------
  {
    int row = tid >> 5;
    int j0  = (tid & 31) * 2;
    float a0 = bh1[j0], a1 = bh1[j0 + 1];
    const float* w0 = Wh1 + j0*128;
    const float* w1 = w0 + 128;
    #pragma unroll 8
    for (int k = 0; k < 128; ++k) {
      float hv = bf2f(sH1f[1][(k >> 5)*512 + ((k >> 3) & 3)*128 + row*8 + (k & 7)]);
      a0 += hv * w0[k];
      a1 += hv * w1[k];
    }
    sXB[row*64 + j0]     = fmaxf(a0, 0.f);
    sXB[row*64 + j0 + 1] = fmaxf(a1, 0.f);
  }
  BAR();
  if (tid < 16) {
    float a = bh2[0];
    #pragma unroll 8
    for (int j = 0; j < 64; ++j) a += sXB[tid*64 + j] * Wh2[j];
    out[b0 + tid] = a;
  }
}

extern "C" void kernel_launch(void* const* d_in, const int* in_sizes, int n_in,
                              void* d_out, int out_size, void* d_ws, size_t ws_size,
                              hipStream_t stream) {
  (void)in_sizes; (void)n_in; (void)d_ws; (void)ws_size; (void)out_size;
  const float* x     = (const float*)d_in[0];
  const float* Wproj = (const float*)d_in[2];
  const float* bproj = (const float*)d_in[3];
  const float* Wih0  = (const float*)d_in[4];
  const float* Whh0  = (const float*)d_in[5];
  const float* bih0  = (const float*)d_in[6];
  const float* bhh0  = (const float*)d_in[7];
  const float* Wih1  = (const float*)d_in[8];
  const float* Whh1  = (const float*)d_in[9];
  const float* bih1  = (const float*)d_in[10];
  const float* bhh1  = (const float*)d_in[11];
  const float* Wh1   = (const float*)d_in[12];
  const float* bh1   = (const float*)d_in[13];
  const float* Wh2   = (const float*)d_in[14];
  const float* bh2   = (const float*)d_in[15];
  float* out = (float*)d_out;

  hipLaunchKernelGGL(fraud_lstm_kernel, dim3(64), dim3(512), 0, stream,
                     x, Wproj, bproj, Wih0, Whh0, bih0, bhh0,
                     Wih1, Whh1, bih1, bhh1, Wh1, bh1, Wh2, bh2, out);
}

// Round 9
// 1789.324 us; speedup vs baseline: 1.1459x; 1.1459x over previous
//
#include <hip/hip_runtime.h>
#include <hip/hip_bf16.h>
#include <stdint.h>

typedef __bf16 bf16x8 __attribute__((ext_vector_type(8)));
typedef float  f32x4  __attribute__((ext_vector_type(4)));

#define BAR()  asm volatile("s_waitcnt lgkmcnt(0)\n\ts_barrier" ::: "memory")
#define SB()   __builtin_amdgcn_sched_barrier(0)

static __device__ __forceinline__ float sigm(float x) {
  return __builtin_amdgcn_rcpf(1.0f + __builtin_amdgcn_exp2f(x * -1.4426950408889634f));
}
static __device__ __forceinline__ float tanh_fast(float x) {
  return 1.0f - 2.0f * __builtin_amdgcn_rcpf(1.0f + __builtin_amdgcn_exp2f(x * 2.8853900817779268f));
}
static __device__ __forceinline__ unsigned short f2bf(float f) {
  return __builtin_bit_cast(unsigned short, (__bf16)f);
}
static __device__ __forceinline__ float bf2f(unsigned short u) {
  union { uint32_t i; float f; } v; v.i = ((uint32_t)u) << 16; return v.f;
}
static __device__ __forceinline__ void async16(const float* g, float* l) {
  __builtin_amdgcn_global_load_lds((__attribute__((address_space(1))) void*)g,
                                   (__attribute__((address_space(3))) void*)l, 16, 0, 0);
}

// 64 WGs x 512 threads persistent; wave wid owns h-cols wid*16..+15 (gate types
// i,f,g,o as its 4 N-tiles). One barrier/step: region t = A(t) + B(t-1).
// Section plan (register ceiling ~250 of 256/wave at 2 waves/SIMD):
//  S1 x-frags(4 reads)+8 MFMA | S2 h0-frags(4)+16 MFMA | S3 wih1 16 MFMA
//  (reuses h0a; h0a dies) + issue h1(4)+wf.kk0(4) | S4 pw0 (covers those
//  reads; acc0 dies) | S5 whh1 4x{4 MFMA, depth-1 wf prefetch} | S6 pw1.
__global__ __launch_bounds__(512) __attribute__((amdgpu_waves_per_eu(2, 2)))
void fraud_lstm_kernel(
    const float* __restrict__ x,     const float* __restrict__ Wproj,
    const float* __restrict__ bproj, const float* __restrict__ Wih0,
    const float* __restrict__ Whh0,  const float* __restrict__ bih0,
    const float* __restrict__ bhh0,  const float* __restrict__ Wih1,
    const float* __restrict__ Whh1,  const float* __restrict__ bih1,
    const float* __restrict__ bhh1,  const float* __restrict__ Wh1,
    const float* __restrict__ bh1,   const float* __restrict__ Wh2,
    const float* __restrict__ bh2,   float* __restrict__ out)
{
  // LDS: 131072 + 8192 + 8192 + 12288 = 159744 B
  __shared__ unsigned short sWf[65536];     // Whh1 frags [wid][n*4+kk][lane][8]; also Wproj stage
  __shared__ unsigned short sH0f[2][2048];  // h0 dbuf, frag-linear [kk][lane][8]
  __shared__ unsigned short sH1f[2][2048];  // h1 dbuf
  __shared__ float sXB[3*1024];             // x triple buffer, frag-linear [kk][half][lane][4]

  const int tid  = threadIdx.x;
  const int lane = tid & 63;
  const int wid  = tid >> 6;
  const int lr   = lane & 15;
  const int lg   = lane >> 4;
  const int b0   = blockIdx.x * 16;
  const int g0   = wid*16 + lr;

  // ---------------- stage Wproj (f32 [64][64]) into sWf ----------------
  {
    float* sWp = reinterpret_cast<float*>(sWf);
    for (int i = tid; i < 4096; i += 512) sWp[i] = Wproj[i];
  }
  BAR();

  // ---------------- fold W0 = Wih0 @ Wproj (per-lane f32); fold biases ----------------
  float w0a[2][4][8];
  #pragma unroll
  for (int kk = 0; kk < 2; ++kk)
    #pragma unroll
    for (int n = 0; n < 4; ++n)
      #pragma unroll
      for (int j = 0; j < 8; ++j) w0a[kk][n][j] = 0.f;
  float bacc[4] = {0.f, 0.f, 0.f, 0.f};
  {
    const float* sWp = reinterpret_cast<const float*>(sWf);
    #pragma unroll 2
    for (int p = 0; p < 64; ++p) {
      float av[4];
      #pragma unroll
      for (int n = 0; n < 4; ++n) av[n] = Wih0[(n*128 + g0)*64 + p];
      float bp = bproj[p];
      #pragma unroll
      for (int n = 0; n < 4; ++n) bacc[n] += av[n] * bp;
      #pragma unroll
      for (int kk = 0; kk < 2; ++kk) {
        f32x4 wa = *(const f32x4*)&sWp[p*64 + kk*32 + lg*8];
        f32x4 wb = *(const f32x4*)&sWp[p*64 + kk*32 + lg*8 + 4];
        #pragma unroll
        for (int n = 0; n < 4; ++n)
          #pragma unroll
          for (int j = 0; j < 4; ++j) {
            w0a[kk][n][j]     += av[n] * wa[j];
            w0a[kk][n][4 + j] += av[n] * wb[j];
          }
      }
    }
  }
  bf16x8 w0f[2][4];
  #pragma unroll
  for (int kk = 0; kk < 2; ++kk)
    #pragma unroll
    for (int n = 0; n < 4; ++n)
      #pragma unroll
      for (int j = 0; j < 8; ++j) w0f[kk][n][j] = (__bf16)w0a[kk][n][j];

  float b0r[4], b1r[4];
  #pragma unroll
  for (int n = 0; n < 4; ++n) {
    const int g = n*128 + g0;
    b0r[n] = bih0[g] + bhh0[g] + bacc[n];
    b1r[n] = bih1[g] + bhh1[g];
  }
  BAR();   // Wproj stage dead; sWf free

  // ---------------- whh0, wih1 -> regs; Whh1 -> LDS frag-linear ----------------
  bf16x8 whh0[4][4], wih1[4][4];
  #pragma unroll
  for (int n = 0; n < 4; ++n)
    #pragma unroll
    for (int kk = 0; kk < 4; ++kk) {
      const int ro = (n*128 + g0)*128 + kk*32 + lg*8;
      const float* p0 = Whh0 + ro;
      const float* p1 = Wih1 + ro;
      #pragma unroll
      for (int j = 0; j < 8; ++j) {
        whh0[n][kk][j] = (__bf16)p0[j];
        wih1[n][kk][j] = (__bf16)p1[j];
      }
    }
  #pragma unroll
  for (int n = 0; n < 4; ++n)
    #pragma unroll
    for (int kk = 0; kk < 4; ++kk) {
      const int ro = (n*128 + g0)*128 + kk*32 + lg*8;
      const float* p2 = Whh1 + ro;
      bf16x8 w;
      #pragma unroll
      for (int j = 0; j < 8; ++j) w[j] = (__bf16)p2[j];
      *(bf16x8*)&sWf[((wid*16 + n*4 + kk)*64 + lane)*8] = w;
    }

  for (int i = tid; i < 2048; i += 512) {
    sH0f[0][i] = 0; sH0f[1][i] = 0; sH1f[0][i] = 0; sH1f[1][i] = 0;
  }

  // ---------------- x staging: frag-linear, per-lane permuted global source ----------------
  const float* xw = x + (size_t)(b0 + (lane & 15)) * (512*64)
                      + ((wid >> 1) & 1) * 32 + (lane >> 4) * 8 + (wid & 1) * 4;
  if (wid < 4) {
    async16(xw,      &sXB[0*1024 + wid*256]);   // x(0) -> buf0
    async16(xw + 64, &sXB[1*1024 + wid*256]);   // x(1) -> buf1
    asm volatile("s_waitcnt vmcnt(1)" ::: "memory");
  }
  BAR();

  const int hwb = (g0 >> 5)*1024 + ((g0 >> 3) & 3)*256 + (g0 & 7)*2 + lg*64;
  const int lb  = lane * 16;

  f32x4 c0r = {0.f,0.f,0.f,0.f}, c1r = {0.f,0.f,0.f,0.f};
  int bufR = 0, bufW = 2;

  // ================ main loop: region t = A(t) + B(t-1), one barrier ================
  #pragma unroll 1
  for (int t = 0; t < 512; ++t) {
    const int cur = t & 1;

    if (wid < 4 && t < 510) async16(xw + (t + 2)*64, &sXB[bufW*1024 + wid*256]);

    const char* xp  = (const char*)sXB + bufR*4096 + lb;
    const char* h0p = (const char*)sH0f[cur ^ 1] + lb;
    const char* h1p = (const char*)sH1f[cur] + lb;
    const char* wp  = (const char*)sWf + wid*16384 + lb;
    char* hw0 = (char*)sH0f[cur] + hwb;

    // ---- S1: x frags + x MFMAs ----
    f32x4 acc0[4];
    #pragma unroll
    for (int n = 0; n < 4; ++n) acc0[n] = f32x4{b0r[n], b0r[n], b0r[n], b0r[n]};
    {
      f32x4 xv0 = *(const f32x4*)(xp);
      f32x4 xv1 = *(const f32x4*)(xp + 1024);
      f32x4 xv2 = *(const f32x4*)(xp + 2048);
      f32x4 xv3 = *(const f32x4*)(xp + 3072);
      bf16x8 xa, xb;
      #pragma unroll
      for (int j = 0; j < 4; ++j) {
        xa[j] = (__bf16)xv0[j]; xa[4+j] = (__bf16)xv1[j];
        xb[j] = (__bf16)xv2[j]; xb[4+j] = (__bf16)xv3[j];
      }
      __builtin_amdgcn_s_setprio(1);
      #pragma unroll
      for (int n = 0; n < 4; ++n)
        acc0[n] = __builtin_amdgcn_mfma_f32_16x16x32_bf16(xa, w0f[0][n], acc0[n], 0, 0, 0);
      #pragma unroll
      for (int n = 0; n < 4; ++n)
        acc0[n] = __builtin_amdgcn_mfma_f32_16x16x32_bf16(xb, w0f[1][n], acc0[n], 0, 0, 0);
      __builtin_amdgcn_s_setprio(0);
    }
    SB();

    // ---- S2: h0 frags + whh0 MFMAs (h0a stays for S3) ----
    bf16x8 h0a0 = *(const bf16x8*)(h0p);
    bf16x8 h0a1 = *(const bf16x8*)(h0p + 1024);
    bf16x8 h0a2 = *(const bf16x8*)(h0p + 2048);
    bf16x8 h0a3 = *(const bf16x8*)(h0p + 3072);
    __builtin_amdgcn_s_setprio(1);
    #pragma unroll
    for (int n = 0; n < 4; ++n)
      acc0[n] = __builtin_amdgcn_mfma_f32_16x16x32_bf16(h0a0, whh0[n][0], acc0[n], 0, 0, 0);
    #pragma unroll
    for (int n = 0; n < 4; ++n)
      acc0[n] = __builtin_amdgcn_mfma_f32_16x16x32_bf16(h0a1, whh0[n][1], acc0[n], 0, 0, 0);
    #pragma unroll
    for (int n = 0; n < 4; ++n)
      acc0[n] = __builtin_amdgcn_mfma_f32_16x16x32_bf16(h0a2, whh0[n][2], acc0[n], 0, 0, 0);
    #pragma unroll
    for (int n = 0; n < 4; ++n)
      acc0[n] = __builtin_amdgcn_mfma_f32_16x16x32_bf16(h0a3, whh0[n][3], acc0[n], 0, 0, 0);
    __builtin_amdgcn_s_setprio(0);
    SB();

    // ---- S3: wih1 (pure register, reuses h0a; h0a dies here) ----
    f32x4 acc1[4];
    #pragma unroll
    for (int n = 0; n < 4; ++n) acc1[n] = f32x4{b1r[n], b1r[n], b1r[n], b1r[n]};
    __builtin_amdgcn_s_setprio(1);
    #pragma unroll
    for (int n = 0; n < 4; ++n)
      acc1[n] = __builtin_amdgcn_mfma_f32_16x16x32_bf16(h0a0, wih1[n][0], acc1[n], 0, 0, 0);
    #pragma unroll
    for (int n = 0; n < 4; ++n)
      acc1[n] = __builtin_amdgcn_mfma_f32_16x16x32_bf16(h0a1, wih1[n][1], acc1[n], 0, 0, 0);
    #pragma unroll
    for (int n = 0; n < 4; ++n)
      acc1[n] = __builtin_amdgcn_mfma_f32_16x16x32_bf16(h0a2, wih1[n][2], acc1[n], 0, 0, 0);
    #pragma unroll
    for (int n = 0; n < 4; ++n)
      acc1[n] = __builtin_amdgcn_mfma_f32_16x16x32_bf16(h0a3, wih1[n][3], acc1[n], 0, 0, 0);
    __builtin_amdgcn_s_setprio(0);
    // issue h1 (4) + wf kk0 (4): latency covered by pw0 (S4)
    bf16x8 h1a0 = *(const bf16x8*)(h1p);
    bf16x8 h1a1 = *(const bf16x8*)(h1p + 1024);
    bf16x8 h1a2 = *(const bf16x8*)(h1p + 2048);
    bf16x8 h1a3 = *(const bf16x8*)(h1p + 3072);
    bf16x8 wfa0 = *(const bf16x8*)(wp);
    bf16x8 wfa1 = *(const bf16x8*)(wp + 4096);
    bf16x8 wfa2 = *(const bf16x8*)(wp + 8192);
    bf16x8 wfa3 = *(const bf16x8*)(wp + 12288);
    SB();

    // ---- S4: pointwise 0 -> h0(t) (acc0 dies) ----
    #pragma unroll
    for (int r = 0; r < 4; ++r) {
      float iv = sigm(acc0[0][r]);
      float fv = sigm(acc0[1][r]);
      float gv = tanh_fast(acc0[2][r]);
      float ov = sigm(acc0[3][r]);
      float c  = fv * c0r[r] + iv * gv;
      c0r[r] = c;
      *(unsigned short*)(hw0 + r*16) = f2bf(ov * tanh_fast(c));
    }
    SB();

    // ---- S5: whh1, depth-1 wf prefetch (acc0 dead; peak live ~248) ----
    {
      // kk = 0 (prefetch kk=1)
      bf16x8 wfb0 = *(const bf16x8*)(wp + 1024);
      bf16x8 wfb1 = *(const bf16x8*)(wp + 4096 + 1024);
      bf16x8 wfb2 = *(const bf16x8*)(wp + 8192 + 1024);
      bf16x8 wfb3 = *(const bf16x8*)(wp + 12288 + 1024);
      __builtin_amdgcn_s_setprio(1);
      acc1[0] = __builtin_amdgcn_mfma_f32_16x16x32_bf16(h1a0, wfa0, acc1[0], 0, 0, 0);
      acc1[1] = __builtin_amdgcn_mfma_f32_16x16x32_bf16(h1a0, wfa1, acc1[1], 0, 0, 0);
      acc1[2] = __builtin_amdgcn_mfma_f32_16x16x32_bf16(h1a0, wfa2, acc1[2], 0, 0, 0);
      acc1[3] = __builtin_amdgcn_mfma_f32_16x16x32_bf16(h1a0, wfa3, acc1[3], 0, 0, 0);
      __builtin_amdgcn_s_setprio(0);
      SB();
      // kk = 1 (prefetch kk=2)
      wfa0 = *(const bf16x8*)(wp + 2048);
      wfa1 = *(const bf16x8*)(wp + 4096 + 2048);
      wfa2 = *(const bf16x8*)(wp + 8192 + 2048);
      wfa3 = *(const bf16x8*)(wp + 12288 + 2048);
      __builtin_amdgcn_s_setprio(1);
      acc1[0] = __builtin_amdgcn_mfma_f32_16x16x32_bf16(h1a1, wfb0, acc1[0], 0, 0, 0);
      acc1[1] = __builtin_amdgcn_mfma_f32_16x16x32_bf16(h1a1, wfb1, acc1[1], 0, 0, 0);
      acc1[2] = __builtin_amdgcn_mfma_f32_16x16x32_bf16(h1a1, wfb2, acc1[2], 0, 0, 0);
      acc1[3] = __builtin_amdgcn_mfma_f32_16x16x32_bf16(h1a1, wfb3, acc1[3], 0, 0, 0);
      __builtin_amdgcn_s_setprio(0);
      SB();
      // kk = 2 (prefetch kk=3)
      wfb0 = *(const bf16x8*)(wp + 3072);
      wfb1 = *(const bf16x8*)(wp + 4096 + 3072);
      wfb2 = *(const bf16x8*)(wp + 8192 + 3072);
      wfb3 = *(const bf16x8*)(wp + 12288 + 3072);
      __builtin_amdgcn_s_setprio(1);
      acc1[0] = __builtin_amdgcn_mfma_f32_16x16x32_bf16(h1a2, wfa0, acc1[0], 0, 0, 0);
      acc1[1] = __builtin_amdgcn_mfma_f32_16x16x32_bf16(h1a2, wfa1, acc1[1], 0, 0, 0);
      acc1[2] = __builtin_amdgcn_mfma_f32_16x16x32_bf16(h1a2, wfa2, acc1[2], 0, 0, 0);
      acc1[3] = __builtin_amdgcn_mfma_f32_16x16x32_bf16(h1a2, wfa3, acc1[3], 0, 0, 0);
      __builtin_amdgcn_s_setprio(0);
      SB();
      // kk = 3
      __builtin_amdgcn_s_setprio(1);
      acc1[0] = __builtin_amdgcn_mfma_f32_16x16x32_bf16(h1a3, wfb0, acc1[0], 0, 0, 0);
      acc1[1] = __builtin_amdgcn_mfma_f32_16x16x32_bf16(h1a3, wfb1, acc1[1], 0, 0, 0);
      acc1[2] = __builtin_amdgcn_mfma_f32_16x16x32_bf16(h1a3, wfb2, acc1[2], 0, 0, 0);
      acc1[3] = __builtin_amdgcn_mfma_f32_16x16x32_bf16(h1a3, wfb3, acc1[3], 0, 0, 0);
      __builtin_amdgcn_s_setprio(0);
      SB();
    }

    // ---- S6: pointwise 1 -> h1(t-1); skipped at t=0 (h1(-1) must stay 0) ----
    if (t > 0) {
      char* hw = (char*)sH1f[cur ^ 1] + hwb;
      #pragma unroll
      for (int r = 0; r < 4; ++r) {
        float iv = sigm(acc1[0][r]);
        float fv = sigm(acc1[1][r]);
        float gv = tanh_fast(acc1[2][r]);
        float ov = sigm(acc1[3][r]);
        float c  = fv * c1r[r] + iv * gv;
        c1r[r] = c;
        *(unsigned short*)(hw + r*16) = f2bf(ov * tanh_fast(c));
      }
    }

    if (wid < 4) {
      if (t < 510) asm volatile("s_waitcnt vmcnt(1)" ::: "memory");
      else         asm volatile("s_waitcnt vmcnt(0)" ::: "memory");
    }
    BAR();   // h0(t), h1(t-1), x(t+1) visible

    bufR = (bufR == 2) ? 0 : bufR + 1;
    bufW = (bufW == 2) ? 0 : bufW + 1;
  }

  // ================ epilogue: B(511) ================
  {
    f32x4 acc1[4];
    #pragma unroll
    for (int n = 0; n < 4; ++n) acc1[n] = f32x4{b1r[n], b1r[n], b1r[n], b1r[n]};
    const char* h0p = (const char*)sH0f[1] + lb;   // h0(511)
    #pragma unroll
    for (int kk = 0; kk < 4; ++kk) {
      bf16x8 ha = *(const bf16x8*)(h0p + kk*1024);
      #pragma unroll
      for (int n = 0; n < 4; ++n)
        acc1[n] = __builtin_amdgcn_mfma_f32_16x16x32_bf16(ha, wih1[n][kk], acc1[n], 0, 0, 0);
    }
    const char* h1p = (const char*)sH1f[0] + lb;   // h1(510)
    const char* wp  = (const char*)sWf + wid*16384 + lb;
    #pragma unroll
    for (int kk = 0; kk < 4; ++kk) {
      bf16x8 ha = *(const bf16x8*)(h1p + kk*1024);
      #pragma unroll
      for (int n = 0; n < 4; ++n) {
        bf16x8 wf = *(const bf16x8*)(wp + (n*4 + kk)*1024);
        acc1[n] = __builtin_amdgcn_mfma_f32_16x16x32_bf16(ha, wf, acc1[n], 0, 0, 0);
      }
    }
    char* hw = (char*)sH1f[1] + hwb;               // h1(511)
    #pragma unroll
    for (int r = 0; r < 4; ++r) {
      float iv = sigm(acc1[0][r]);
      float fv = sigm(acc1[1][r]);
      float gv = tanh_fast(acc1[2][r]);
      float ov = sigm(acc1[3][r]);
      float c  = fv * c1r[r] + iv * gv;
      c1r[r] = c;
      *(unsigned short*)(hw + r*16) = f2bf(ov * tanh_fast(c));
    }
    BAR();
  }

  // ---------------- head: hid = relu(h1@Wh1^T + bh1); out = hid@Wh2^T + bh2 ----------------
  {
    int row = tid >> 5;
    int j0  = (tid & 31) * 2;
    float a0 = bh1[j0], a1 = bh1[j0 + 1];
    const float* w0 = Wh1 + j0*128;
    const float* w1 = w0 + 128;
    #pragma unroll 8
    for (int k = 0; k < 128; ++k) {
      float hv = bf2f(sH1f[1][(k >> 5)*512 + ((k >> 3) & 3)*128 + row*8 + (k & 7)]);
      a0 += hv * w0[k];
      a1 += hv * w1[k];
    }
    sXB[row*64 + j0]     = fmaxf(a0, 0.f);
    sXB[row*64 + j0 + 1] = fmaxf(a1, 0.f);
  }
  BAR();
  if (tid < 16) {
    float a = bh2[0];
    #pragma unroll 8
    for (int j = 0; j < 64; ++j) a += sXB[tid*64 + j] * Wh2[j];
    out[b0 + tid] = a;
  }
}

extern "C" void kernel_launch(void* const* d_in, const int* in_sizes, int n_in,
                              void* d_out, int out_size, void* d_ws, size_t ws_size,
                              hipStream_t stream) {
  (void)in_sizes; (void)n_in; (void)d_ws; (void)ws_size; (void)out_size;
  const float* x     = (const float*)d_in[0];
  const float* Wproj = (const float*)d_in[2];
  const float* bproj = (const float*)d_in[3];
  const float* Wih0  = (const float*)d_in[4];
  const float* Whh0  = (const float*)d_in[5];
  const float* bih0  = (const float*)d_in[6];
  const float* bhh0  = (const float*)d_in[7];
  const float* Wih1  = (const float*)d_in[8];
  const float* Whh1  = (const float*)d_in[9];
  const float* bih1  = (const float*)d_in[10];
  const float* bhh1  = (const float*)d_in[11];
  const float* Wh1   = (const float*)d_in[12];
  const float* bh1   = (const float*)d_in[13];
  const float* Wh2   = (const float*)d_in[14];
  const float* bh2   = (const float*)d_in[15];
  float* out = (float*)d_out;

  hipLaunchKernelGGL(fraud_lstm_kernel, dim3(64), dim3(512), 0, stream,
                     x, Wproj, bproj, Wih0, Whh0, bih0, bhh0,
                     Wih1, Whh1, bih1, bhh1, Wh1, bh1, Wh2, bh2, out);
}

// Round 10
// 1115.950 us; speedup vs baseline: 1.8374x; 1.6034x over previous
//
#include <hip/hip_runtime.h>
#include <hip/hip_bf16.h>
#include <stdint.h>

typedef __bf16 bf16x8 __attribute__((ext_vector_type(8)));
typedef float  f32x4  __attribute__((ext_vector_type(4)));

#define BAR()  asm volatile("s_waitcnt lgkmcnt(0)\n\ts_barrier" ::: "memory")
#define SB()   __builtin_amdgcn_sched_barrier(0)

static __device__ __forceinline__ float sigm(float x) {
  return __builtin_amdgcn_rcpf(1.0f + __builtin_amdgcn_exp2f(x * -1.4426950408889634f));
}
static __device__ __forceinline__ float tanh_fast(float x) {
  return 1.0f - 2.0f * __builtin_amdgcn_rcpf(1.0f + __builtin_amdgcn_exp2f(x * 2.8853900817779268f));
}
static __device__ __forceinline__ unsigned short f2bf(float f) {
  return __builtin_bit_cast(unsigned short, (__bf16)f);
}
static __device__ __forceinline__ float bf2f(unsigned short u) {
  union { uint32_t i; float f; } v; v.i = ((uint32_t)u) << 16; return v.f;
}
static __device__ __forceinline__ void async16(const float* g, float* l) {
  __builtin_amdgcn_global_load_lds((__attribute__((address_space(1))) void*)g,
                                   (__attribute__((address_space(3))) void*)l, 16, 0, 0);
}

// 64 WGs x 512 threads persistent; wave wid owns h-cols wid*16..+15 (gate types
// i,f,g,o as its 4 N-tiles). One barrier/step: region t = A(t) + B(t-1), which
// are data-independent within the region (B consumes only last-region buffers).
// PHASE SKEW: waves 0-3 execute A;B, waves 4-7 execute B;A -> each SIMD hosts
// one A-phase and one B-phase wave, so MFMA/trans/LDS usage is complementary
// instead of lockstep-aligned (R7 kernel otherwise byte-identical, 1125 us).
#define SEC_A() do {                                                           \
    f32x4 acc0[4];                                                             \
    _Pragma("unroll")                                                          \
    for (int n = 0; n < 4; ++n) acc0[n] = f32x4{b0r[n],b0r[n],b0r[n],b0r[n]};  \
    _Pragma("unroll")                                                          \
    for (int kk = 0; kk < 2; ++kk) {                                           \
      f32x4 a0 = *(const f32x4*)(xp + kk*2048);                                \
      f32x4 a1 = *(const f32x4*)(xp + kk*2048 + 1024);                         \
      bf16x8 xa;                                                               \
      _Pragma("unroll")                                                        \
      for (int j = 0; j < 4; ++j) { xa[j] = (__bf16)a0[j]; xa[4+j] = (__bf16)a1[j]; } \
      _Pragma("unroll")                                                        \
      for (int n = 0; n < 4; ++n)                                              \
        acc0[n] = __builtin_amdgcn_mfma_f32_16x16x32_bf16(xa, w0f[kk][n], acc0[n], 0, 0, 0); \
      SB();                                                                    \
    }                                                                          \
    _Pragma("unroll")                                                          \
    for (int kk = 0; kk < 4; ++kk) {                                           \
      bf16x8 ha = *(const bf16x8*)(h0p + kk*1024);                             \
      _Pragma("unroll")                                                        \
      for (int n = 0; n < 4; ++n)                                              \
        acc0[n] = __builtin_amdgcn_mfma_f32_16x16x32_bf16(ha, whh0[n][kk], acc0[n], 0, 0, 0); \
      SB();                                                                    \
    }                                                                          \
    _Pragma("unroll")                                                          \
    for (int r = 0; r < 4; ++r) {                                              \
      float iv = sigm(acc0[0][r]);                                             \
      float fv = sigm(acc0[1][r]);                                             \
      float gv = tanh_fast(acc0[2][r]);                                        \
      float ov = sigm(acc0[3][r]);                                             \
      float c  = fv * c0r[r] + iv * gv;                                        \
      c0r[r] = c;                                                              \
      *(unsigned short*)(hw0 + r*16) = f2bf(ov * tanh_fast(c));                \
    }                                                                          \
    SB();                                                                      \
  } while (0)

#define SEC_B() do {                                                           \
    f32x4 acc1[4];                                                             \
    _Pragma("unroll")                                                          \
    for (int n = 0; n < 4; ++n) acc1[n] = f32x4{b1r[n],b1r[n],b1r[n],b1r[n]};  \
    _Pragma("unroll")                                                          \
    for (int kk = 0; kk < 4; ++kk) {                                           \
      bf16x8 ha = *(const bf16x8*)(h0p + kk*1024);                             \
      _Pragma("unroll")                                                        \
      for (int n = 0; n < 4; ++n)                                              \
        acc1[n] = __builtin_amdgcn_mfma_f32_16x16x32_bf16(ha, wih1[n][kk], acc1[n], 0, 0, 0); \
      SB();                                                                    \
    }                                                                          \
    _Pragma("unroll")                                                          \
    for (int kk = 0; kk < 4; ++kk) {                                           \
      bf16x8 ha = *(const bf16x8*)(h1p + kk*1024);                             \
      _Pragma("unroll")                                                        \
      for (int n = 0; n < 4; ++n) {                                            \
        bf16x8 wf = *(const bf16x8*)(wp + (n*4 + kk)*1024);                    \
        acc1[n] = __builtin_amdgcn_mfma_f32_16x16x32_bf16(ha, wf, acc1[n], 0, 0, 0); \
      }                                                                        \
      SB();                                                                    \
    }                                                                          \
    if (t > 0) {                                                               \
      char* hw = (char*)sH1f[cur ^ 1] + hwb;                                   \
      _Pragma("unroll")                                                        \
      for (int r = 0; r < 4; ++r) {                                            \
        float iv = sigm(acc1[0][r]);                                           \
        float fv = sigm(acc1[1][r]);                                           \
        float gv = tanh_fast(acc1[2][r]);                                      \
        float ov = sigm(acc1[3][r]);                                           \
        float c  = fv * c1r[r] + iv * gv;                                      \
        c1r[r] = c;                                                            \
        *(unsigned short*)(hw + r*16) = f2bf(ov * tanh_fast(c));               \
      }                                                                        \
    }                                                                          \
    SB();                                                                      \
  } while (0)

__global__ __launch_bounds__(512) __attribute__((amdgpu_waves_per_eu(2, 2)))
void fraud_lstm_kernel(
    const float* __restrict__ x,     const float* __restrict__ Wproj,
    const float* __restrict__ bproj, const float* __restrict__ Wih0,
    const float* __restrict__ Whh0,  const float* __restrict__ bih0,
    const float* __restrict__ bhh0,  const float* __restrict__ Wih1,
    const float* __restrict__ Whh1,  const float* __restrict__ bih1,
    const float* __restrict__ bhh1,  const float* __restrict__ Wh1,
    const float* __restrict__ bh1,   const float* __restrict__ Wh2,
    const float* __restrict__ bh2,   float* __restrict__ out)
{
  // LDS: 131072 + 8192 + 8192 + 12288 = 159744 B
  __shared__ unsigned short sWf[65536];     // Whh1 frags [wid][n*4+kk][lane][8]; also Wproj stage
  __shared__ unsigned short sH0f[2][2048];  // h0 dbuf, frag-linear [kk][lane][8]
  __shared__ unsigned short sH1f[2][2048];  // h1 dbuf
  __shared__ float sXB[3*1024];             // x triple buffer, frag-linear [kk][half][lane][4]

  const int tid  = threadIdx.x;
  const int lane = tid & 63;
  const int wid  = tid >> 6;
  const int lr   = lane & 15;
  const int lg   = lane >> 4;
  const int b0   = blockIdx.x * 16;
  const int g0   = wid*16 + lr;

  // ---------------- stage Wproj (f32 [64][64]) into sWf ----------------
  {
    float* sWp = reinterpret_cast<float*>(sWf);
    for (int i = tid; i < 4096; i += 512) sWp[i] = Wproj[i];
  }
  BAR();

  // ---------------- fold W0 = Wih0 @ Wproj (per-lane f32); fold biases ----------------
  float w0a[2][4][8];
  #pragma unroll
  for (int kk = 0; kk < 2; ++kk)
    #pragma unroll
    for (int n = 0; n < 4; ++n)
      #pragma unroll
      for (int j = 0; j < 8; ++j) w0a[kk][n][j] = 0.f;
  float bacc[4] = {0.f, 0.f, 0.f, 0.f};
  {
    const float* sWp = reinterpret_cast<const float*>(sWf);
    #pragma unroll 2
    for (int p = 0; p < 64; ++p) {
      float av[4];
      #pragma unroll
      for (int n = 0; n < 4; ++n) av[n] = Wih0[(n*128 + g0)*64 + p];
      float bp = bproj[p];
      #pragma unroll
      for (int n = 0; n < 4; ++n) bacc[n] += av[n] * bp;
      #pragma unroll
      for (int kk = 0; kk < 2; ++kk) {
        f32x4 wa = *(const f32x4*)&sWp[p*64 + kk*32 + lg*8];
        f32x4 wb = *(const f32x4*)&sWp[p*64 + kk*32 + lg*8 + 4];
        #pragma unroll
        for (int n = 0; n < 4; ++n)
          #pragma unroll
          for (int j = 0; j < 4; ++j) {
            w0a[kk][n][j]     += av[n] * wa[j];
            w0a[kk][n][4 + j] += av[n] * wb[j];
          }
      }
    }
  }
  bf16x8 w0f[2][4];
  #pragma unroll
  for (int kk = 0; kk < 2; ++kk)
    #pragma unroll
    for (int n = 0; n < 4; ++n)
      #pragma unroll
      for (int j = 0; j < 8; ++j) w0f[kk][n][j] = (__bf16)w0a[kk][n][j];

  float b0r[4], b1r[4];
  #pragma unroll
  for (int n = 0; n < 4; ++n) {
    const int g = n*128 + g0;
    b0r[n] = bih0[g] + bhh0[g] + bacc[n];
    b1r[n] = bih1[g] + bhh1[g];
  }
  BAR();   // Wproj stage dead; sWf free

  // ---------------- whh0, wih1 -> regs; Whh1 -> LDS frag-linear ----------------
  bf16x8 whh0[4][4], wih1[4][4];
  #pragma unroll
  for (int n = 0; n < 4; ++n)
    #pragma unroll
    for (int kk = 0; kk < 4; ++kk) {
      const int ro = (n*128 + g0)*128 + kk*32 + lg*8;
      const float* p0 = Whh0 + ro;
      const float* p1 = Wih1 + ro;
      #pragma unroll
      for (int j = 0; j < 8; ++j) {
        whh0[n][kk][j] = (__bf16)p0[j];
        wih1[n][kk][j] = (__bf16)p1[j];
      }
    }
  #pragma unroll
  for (int n = 0; n < 4; ++n)
    #pragma unroll
    for (int kk = 0; kk < 4; ++kk) {
      const int ro = (n*128 + g0)*128 + kk*32 + lg*8;
      const float* p2 = Whh1 + ro;
      bf16x8 w;
      #pragma unroll
      for (int j = 0; j < 8; ++j) w[j] = (__bf16)p2[j];
      *(bf16x8*)&sWf[((wid*16 + n*4 + kk)*64 + lane)*8] = w;
    }

  for (int i = tid; i < 2048; i += 512) {
    sH0f[0][i] = 0; sH0f[1][i] = 0; sH1f[0][i] = 0; sH1f[1][i] = 0;
  }

  // ---------------- x staging: frag-linear, per-lane permuted global source ----------------
  const float* xw = x + (size_t)(b0 + (lane & 15)) * (512*64)
                      + ((wid >> 1) & 1) * 32 + (lane >> 4) * 8 + (wid & 1) * 4;
  if (wid < 4) {
    async16(xw,      &sXB[0*1024 + wid*256]);   // x(0) -> buf0
    async16(xw + 64, &sXB[1*1024 + wid*256]);   // x(1) -> buf1
    asm volatile("s_waitcnt vmcnt(1)" ::: "memory");
  }
  BAR();

  const int hwb = (g0 >> 5)*1024 + ((g0 >> 3) & 3)*256 + (g0 & 7)*2 + lg*64;
  const int lb  = lane * 16;

  f32x4 c0r = {0.f,0.f,0.f,0.f}, c1r = {0.f,0.f,0.f,0.f};
  int bufR = 0, bufW = 2;

  // ================ main loop: region t = A(t) + B(t-1), one barrier ================
  #pragma unroll 1
  for (int t = 0; t < 512; ++t) {
    const int cur = t & 1;

    if (wid < 4 && t < 510) async16(xw + (t + 2)*64, &sXB[bufW*1024 + wid*256]);

    const char* xp  = (const char*)sXB + bufR*4096 + lb;
    const char* h0p = (const char*)sH0f[cur ^ 1] + lb;
    const char* h1p = (const char*)sH1f[cur] + lb;
    const char* wp  = (const char*)sWf + wid*16384 + lb;
    char* hw0 = (char*)sH0f[cur] + hwb;

    if (wid < 4) { SEC_A(); SEC_B(); }
    else         { SEC_B(); SEC_A(); }

    if (wid < 4) {
      if (t < 510) asm volatile("s_waitcnt vmcnt(1)" ::: "memory");
      else         asm volatile("s_waitcnt vmcnt(0)" ::: "memory");
    }
    BAR();   // h0(t), h1(t-1), x(t+1) visible

    bufR = (bufR == 2) ? 0 : bufR + 1;
    bufW = (bufW == 2) ? 0 : bufW + 1;
  }

  // ================ epilogue: B(511) ================
  {
    f32x4 acc1[4];
    #pragma unroll
    for (int n = 0; n < 4; ++n) acc1[n] = f32x4{b1r[n], b1r[n], b1r[n], b1r[n]};
    const char* h0p = (const char*)sH0f[1] + lb;   // h0(511)
    #pragma unroll
    for (int kk = 0; kk < 4; ++kk) {
      bf16x8 ha = *(const bf16x8*)(h0p + kk*1024);
      #pragma unroll
      for (int n = 0; n < 4; ++n)
        acc1[n] = __builtin_amdgcn_mfma_f32_16x16x32_bf16(ha, wih1[n][kk], acc1[n], 0, 0, 0);
    }
    const char* h1p = (const char*)sH1f[0] + lb;   // h1(510)
    const char* wp  = (const char*)sWf + wid*16384 + lb;
    #pragma unroll
    for (int kk = 0; kk < 4; ++kk) {
      bf16x8 ha = *(const bf16x8*)(h1p + kk*1024);
      #pragma unroll
      for (int n = 0; n < 4; ++n) {
        bf16x8 wf = *(const bf16x8*)(wp + (n*4 + kk)*1024);
        acc1[n] = __builtin_amdgcn_mfma_f32_16x16x32_bf16(ha, wf, acc1[n], 0, 0, 0);
      }
    }
    char* hw = (char*)sH1f[1] + hwb;               // h1(511)
    #pragma unroll
    for (int r = 0; r < 4; ++r) {
      float iv = sigm(acc1[0][r]);
      float fv = sigm(acc1[1][r]);
      float gv = tanh_fast(acc1[2][r]);
      float ov = sigm(acc1[3][r]);
      float c  = fv * c1r[r] + iv * gv;
      c1r[r] = c;
      *(unsigned short*)(hw + r*16) = f2bf(ov * tanh_fast(c));
    }
    BAR();
  }

  // ---------------- head: hid = relu(h1@Wh1^T + bh1); out = hid@Wh2^T + bh2 ----------------
  {
    int row = tid >> 5;
    int j0  = (tid & 31) * 2;
    float a0 = bh1[j0], a1 = bh1[j0 + 1];
    const float* w0 = Wh1 + j0*128;
    const float* w1 = w0 + 128;
    #pragma unroll 8
    for (int k = 0; k < 128; ++k) {
      float hv = bf2f(sH1f[1][(k >> 5)*512 + ((k >> 3) & 3)*128 + row*8 + (k & 7)]);
      a0 += hv * w0[k];
      a1 += hv * w1[k];
    }
    sXB[row*64 + j0]     = fmaxf(a0, 0.f);
    sXB[row*64 + j0 + 1] = fmaxf(a1, 0.f);
  }
  BAR();
  if (tid < 16) {
    float a = bh2[0];
    #pragma unroll 8
    for (int j = 0; j < 64; ++j) a += sXB[tid*64 + j] * Wh2[j];
    out[b0 + tid] = a;
  }
}

extern "C" void kernel_launch(void* const* d_in, const int* in_sizes, int n_in,
                              void* d_out, int out_size, void* d_ws, size_t ws_size,
                              hipStream_t stream) {
  (void)in_sizes; (void)n_in; (void)d_ws; (void)ws_size; (void)out_size;
  const float* x     = (const float*)d_in[0];
  const float* Wproj = (const float*)d_in[2];
  const float* bproj = (const float*)d_in[3];
  const float* Wih0  = (const float*)d_in[4];
  const float* Whh0  = (const float*)d_in[5];
  const float* bih0  = (const float*)d_in[6];
  const float* bhh0  = (const float*)d_in[7];
  const float* Wih1  = (const float*)d_in[8];
  const float* Whh1  = (const float*)d_in[9];
  const float* bih1  = (const float*)d_in[10];
  const float* bhh1  = (const float*)d_in[11];
  const float* Wh1   = (const float*)d_in[12];
  const float* bh1   = (const float*)d_in[13];
  const float* Wh2   = (const float*)d_in[14];
  const float* bh2   = (const float*)d_in[15];
  float* out = (float*)d_out;

  hipLaunchKernelGGL(fraud_lstm_kernel, dim3(64), dim3(512), 0, stream,
                     x, Wproj, bproj, Wih0, Whh0, bih0, bhh0,
                     Wih1, Whh1, bih1, bhh1, Wh1, bh1, Wh2, bh2, out);
}